// Round 5
// baseline (2627.974 us; speedup 1.0000x reference)
//
#include <hip/hip_runtime.h>
#include <hip/hip_bf16.h>
#include <math.h>

// RTM identities:
//  - softmax over size-1 axis == 1  =>  q,k,Wq,Wk dead; newV == v
//  - token j restarts from s0[:,j]; only cumV couples tokens
//  - prefix-sum linear => fold Wv into Wo: Wvo[a] = Wo[a] @ Wv[a] (once);
//       S1 = PS(LN1(T)) @ Wvo[a]^T + T
// R5 GEMM core: NO LDS. In the NT layout the MFMA fragments are contiguous
// 16B global loads (row = lane&15, kchunk = lane>>4). Loading them straight
// into VGPRs removes every barrier/LDS op from the K-loop -> compiler emits a
// software-pipelined load->MFMA stream with fine-grained vmcnt (the thing
// __syncthreads structurally forbids; R3/R4 swizzle+dbuf were neutral).
// 2x2-wave blocks give L1 reuse; all grids 720-768 blocks (3/CU).

using bf16   = __bf16;
using bf16x8 = __attribute__((ext_vector_type(8))) __bf16;
using f32x4  = __attribute__((ext_vector_type(4))) float;

#define DEV __device__ __forceinline__

// GELU with A&S 7.1.26 erf (abs err 1.5e-7; << bf16 rounding).
DEV float gelu_f(float x) {
  const float y  = x * 0.70710678118654752f;
  const float ay = fabsf(y);
  const float t  = __builtin_amdgcn_rcpf(__builtin_fmaf(0.3275911f, ay, 1.0f));
  float p = __builtin_fmaf(1.061405429f, t, -1.453152027f);
  p = __builtin_fmaf(p, t, 1.421413741f);
  p = __builtin_fmaf(p, t, -0.284496736f);
  p = __builtin_fmaf(p, t, 0.254829592f);
  p = p * t;
  const float e = __expf(-ay * ay);
  float er = __builtin_fmaf(-p, e, 1.0f);
  er = __builtin_copysignf(er, y);
  return 0.5f * x * (1.0f + er);
}

enum { EPI_PART = 0, EPI_GELU = 1, EPI_B16 = 2 };

// C[BM x 128 tile] = A[M,K(+z*aZ)] @ B[N,K(+z*bZ)]^T over k in [z*kZ, z*kZ+klen).
// Direct-fragment GEMM: no LDS, no barriers. 4 waves in a 2x2 grid; wave tile
// (BM/2) x 64. Requires klen % 64 == 0 (all call sites satisfy this).
template <int BM, int EPI>
__global__ __launch_bounds__(256, 3) void gemm_d(
    const bf16* __restrict__ A, const bf16* __restrict__ B,
    float* __restrict__ outF, bf16* __restrict__ outB,
    const float* __restrict__ aux, int K, int N,
    int kZ, int klen, size_t aZ, size_t bZ, size_t oZ)
{
  constexpr int MT = BM / 32;   // 4 (BM=128) or 2 (BM=64)
  constexpr int NT = 4;
  const int z = blockIdx.z;
  A += (size_t)z * aZ;
  B += (size_t)z * bZ;
  const int kbeg = z * kZ;
  const int tid  = threadIdx.x;
  const int lane = tid & 63, wave = tid >> 6;
  const int m0 = blockIdx.x * BM, n0 = blockIdx.y * 128;
  const int wr = (wave & 1) * (BM / 2), wc = (wave >> 1) * 64;
  const int lr = lane & 15, kb = lane >> 4;

  const bf16* aP[MT];
  const bf16* bP[NT];
#pragma unroll
  for (int t = 0; t < MT; ++t)
    aP[t] = A + (size_t)(m0 + wr + t * 16 + lr) * K + kb * 8 + kbeg;
#pragma unroll
  for (int t = 0; t < NT; ++t)
    bP[t] = B + (size_t)(n0 + wc + t * 16 + lr) * K + kb * 8 + kbeg;

  f32x4 acc[MT][NT] = {};
  bf16x8 aA[MT], bA[NT], aB[MT], bB[NT];

  auto ldfrag = [&](bf16x8* af, bf16x8* bf, int k) {
#pragma unroll
    for (int t = 0; t < MT; ++t) af[t] = *(const bf16x8*)(aP[t] + k);
#pragma unroll
    for (int t = 0; t < NT; ++t) bf[t] = *(const bf16x8*)(bP[t] + k);
  };
  auto domfma = [&](bf16x8* af, bf16x8* bf) {
#pragma unroll
    for (int mt = 0; mt < MT; ++mt)
#pragma unroll
      for (int nt = 0; nt < NT; ++nt)
        acc[mt][nt] = __builtin_amdgcn_mfma_f32_16x16x32_bf16(af[mt], bf[nt], acc[mt][nt], 0, 0, 0);
  };

  ldfrag(aA, bA, 0);
  for (int k0 = 0; k0 < klen; k0 += 64) {
    ldfrag(aB, bB, k0 + 32);           // overlaps MFMA(aA) below
    domfma(aA, bA);
    if (k0 + 64 < klen) ldfrag(aA, bA, k0 + 64);
    domfma(aB, bB);
  }

  // C/D layout: col = lane&15, row = (lane>>4)*4 + reg  [verified m89/m91]
  const int row0 = m0 + wr + (lane >> 4) * 4;
  const int col0 = n0 + wc + lr;
  float* oF = (EPI == EPI_PART) ? outF + (size_t)z * oZ : nullptr;
  bf16*  oB = (EPI == EPI_B16)  ? outB + (size_t)z * oZ : outB;
#pragma unroll
  for (int mt = 0; mt < MT; ++mt) {
#pragma unroll
    for (int nt = 0; nt < NT; ++nt) {
      const int col = col0 + nt * 16;
      float bias = 0.f;
      if (EPI == EPI_GELU) bias = aux[col];
#pragma unroll
      for (int rg = 0; rg < 4; ++rg) {
        const int row = row0 + mt * 16 + rg;
        float v = acc[mt][nt][rg];
        if (EPI == EPI_PART) {
          oF[(size_t)row * N + col] = v;
        } else if (EPI == EPI_GELU) {
          oB[(size_t)row * N + col] = (bf16)gelu_f(v + bias);
        } else {
          oB[(size_t)row * N + col] = (bf16)v;
        }
      }
    }
  }
}

// One 768-row per block; sums NP split-K partials, adds per-MODE term, LN-fuses.
// MODE 0: s = Σp + PE[row&255]; T=s; SN = LN1(s)
// MODE 1: s = Σp + add[row]   ; SN = LN2(s)+s
// MODE 2: s = Σp + bias       ; T=s; SN = LN1(s)
// MODE 3: s = Σp + bias       ; T=s (fp32 out only, last stage)
template <int NP, int MODE>
__global__ __launch_bounds__(256) void reduce_ln(
    const float* __restrict__ P, size_t pZ,
    const float* __restrict__ add, const float* __restrict__ g,
    const float* __restrict__ b, float* __restrict__ Tout,
    bf16* __restrict__ SNout)
{
  const int row = blockIdx.x, t = threadIdx.x;
  float v[3];
#pragma unroll
  for (int c = 0; c < 3; ++c) {
    const int col = t + c * 256;
    float s = P[(size_t)row * 768 + col];
#pragma unroll
    for (int p = 1; p < NP; ++p) s += P[(size_t)p * pZ + (size_t)row * 768 + col];
    if (MODE == 0) s += add[(row & 255) * 768 + col];
    if (MODE == 1) s += add[(size_t)row * 768 + col];
    if (MODE == 2 || MODE == 3) s += add[col];
    v[c] = s;
  }
  if (MODE != 1) {
#pragma unroll
    for (int c = 0; c < 3; ++c) Tout[(size_t)row * 768 + t + c * 256] = v[c];
  }
  if (MODE == 3) return;

  __shared__ float red[8];
  float s = v[0] + v[1] + v[2];
#pragma unroll
  for (int o = 32; o >= 1; o >>= 1) s += __shfl_down(s, o);
  if ((t & 63) == 0) red[t >> 6] = s;
  __syncthreads();
  const float mu = (red[0] + red[1] + red[2] + red[3]) * (1.f / 768.f);
  const float d0 = v[0] - mu, d1 = v[1] - mu, d2 = v[2] - mu;
  float q = d0 * d0 + d1 * d1 + d2 * d2;
#pragma unroll
  for (int o = 32; o >= 1; o >>= 1) q += __shfl_down(q, o);
  if ((t & 63) == 0) red[4 + (t >> 6)] = q;
  __syncthreads();
  const float var = (red[4] + red[5] + red[6] + red[7]) * (1.f / 768.f);
  const float rs = rsqrtf(var + 1e-5f);
  float y0 = d0 * rs * g[t] + b[t];
  float y1 = d1 * rs * g[t + 256] + b[t + 256];
  float y2 = d2 * rs * g[t + 512] + b[t + 512];
  if (MODE == 1) { y0 += v[0]; y1 += v[1]; y2 += v[2]; }
  bf16* o = SNout + (size_t)row * 768;
  o[t] = (bf16)y0; o[t + 256] = (bf16)y1; o[t + 512] = (bf16)y2;
}

// Fused exclusive prefix over token axis j (256 tokens) of SN[n,j,d].
// grid (16 n, 3 dgrp); thread owns one d, walks 256 tokens.
__global__ __launch_bounds__(256) void scan_k(
    const bf16* __restrict__ SN, bf16* __restrict__ PSb)
{
  const int n = blockIdx.x, d = blockIdx.y * 256 + threadIdx.x;
  const bf16* s = SN + (size_t)n * 256 * 768 + d;
  bf16* o = PSb + (size_t)n * 256 * 768 + d;
  float run = 0.f;
#pragma unroll 8
  for (int j = 0; j < 256; ++j) {
    const float v = (float)s[(size_t)j * 768];
    o[(size_t)j * 768] = (bf16)run;
    run += v;
  }
}

// WvT[a][n][k] = (bf16)Wv[a][k][n]; 64x64 tiles via LDS (65-float stride).
__global__ __launch_bounds__(256) void transpose_wv(
    const float* __restrict__ Wv, bf16* __restrict__ WvT)
{
  __shared__ float tile[64][65];
  const int a = blockIdx.z, k0 = blockIdx.x * 64, n0 = blockIdx.y * 64;
  const int c = threadIdx.x & 63, r4 = threadIdx.x >> 6;
  const float* src = Wv + (size_t)a * 589824;
  bf16* dst = WvT + (size_t)a * 589824;
#pragma unroll
  for (int i = 0; i < 16; ++i)
    tile[r4 + i * 4][c] = src[(size_t)(k0 + r4 + i * 4) * 768 + n0 + c];
  __syncthreads();
#pragma unroll
  for (int i = 0; i < 16; ++i) {
    const int n = r4 + i * 4;
    dst[(size_t)(n0 + n) * 768 + k0 + c] = (bf16)tile[c][n];
  }
}

__global__ __launch_bounds__(256) void f32_to_bf16_k(
    const float* __restrict__ in, bf16* __restrict__ out, int n4)
{
  const int i = blockIdx.x * 256 + threadIdx.x;
  if (i >= n4) return;
  const float4 v = ((const float4*)in)[i];
  bf16 h[4] = {(bf16)v.x, (bf16)v.y, (bf16)v.z, (bf16)v.w};
  *(uint2*)(out + 4 * (size_t)i) = *(uint2*)h;
}

// pe[j, 2p] = sin(j / 10000^(4p/768)),  pe[j, 2p+1] = cos(...)
__global__ __launch_bounds__(256) void pe_kernel(float* __restrict__ PE)
{
  const int id = blockIdx.x * 256 + threadIdx.x;  // 256*384 total
  const int j = id / 384, p = id % 384;
  const double ang = (double)j * pow(10000.0, -4.0 * (double)p / 768.0);
  PE[(size_t)j * 768 + 2 * p]     = (float)sin(ang);
  PE[(size_t)j * 768 + 2 * p + 1] = (float)cos(ang);
}

extern "C" void kernel_launch(void* const* d_in, const int* in_sizes, int n_in,
                              void* d_out, int out_size, void* d_ws, size_t ws_size,
                              hipStream_t stream)
{
  const float* x      = (const float*)d_in[0];
  const float* weight = (const float*)d_in[1];
  const float* Wv     = (const float*)d_in[4];
  const float* Wo     = (const float*)d_in[5];
  const float* ln1g   = (const float*)d_in[6];
  const float* ln1b   = (const float*)d_in[7];
  const float* ln2g   = (const float*)d_in[8];
  const float* ln2b   = (const float*)d_in[9];
  const float* fc1w   = (const float*)d_in[10];
  const float* fc1b   = (const float*)d_in[11];
  const float* fc2w   = (const float*)d_in[12];
  const float* fc2b   = (const float*)d_in[13];
  float* out = (float*)d_out;

  char* p = (char*)d_ws;
  auto alloc = [&](size_t bytes) { char* r = p; p += (bytes + 255) & ~(size_t)255; return r; };
  bf16*  Wb_w  = (bf16*)alloc(589824ull * 2);
  bf16*  Wb_o  = (bf16*)alloc(5898240ull * 2);
  bf16*  WvT   = (bf16*)alloc(5898240ull * 2);
  bf16*  Wvo   = (bf16*)alloc(5898240ull * 2);
  bf16*  Wb_f1 = (bf16*)alloc(2359296ull * 2);
  bf16*  Wb_f2 = (bf16*)alloc(2359296ull * 2);
  bf16*  Xb    = (bf16*)alloc(3145728ull * 2);
  float* PEf   = (float*)alloc(196608ull * 4);
  float* T     = (float*)alloc(3145728ull * 4);
  bf16*  SN    = (bf16*)alloc(3145728ull * 2);
  bf16*  PSb   = (bf16*)alloc(3145728ull * 2);
  bf16*  H     = (bf16*)alloc(12582912ull * 2);
  float* Part  = (float*)alloc(2ull * 3145728ull * 4);

  auto cvt = [&](const float* src, bf16* dst, int n) {
    int n4 = n / 4;
    f32_to_bf16_k<<<(n4 + 255) / 256, 256, 0, stream>>>(src, dst, n4);
  };
  cvt(x, Xb, 3145728);
  cvt(weight, Wb_w, 589824);
  cvt(Wo, Wb_o, 5898240);
  cvt(fc1w, Wb_f1, 2359296);
  cvt(fc2w, Wb_f2, 2359296);
  transpose_wv<<<dim3(12, 12, 10), 256, 0, stream>>>(Wv, WvT);
  pe_kernel<<<384, 256, 0, stream>>>(PEf);

  // Wvo[a] = Wo[a] @ Wv[a]  (A = Wo[a][m,t], B = WvT[a][k,t], batched over z)
  gemm_d<64, EPI_B16><<<dim3(12, 6, 10), 256, 0, stream>>>(
      Wb_o, WvT, nullptr, Wvo, nullptr, 768, 768, 0, 768, 589824, 589824, 589824);

  // T0 = x @ weight^T + PE (split-K x2), fused LN1
  gemm_d<64, EPI_PART><<<dim3(64, 6, 2), 256, 0, stream>>>(
      Xb, Wb_w, Part, nullptr, nullptr, 768, 768, 384, 384, 0, 0, 3145728);
  reduce_ln<2, 0><<<4096, 256, 0, stream>>>(Part, 3145728, PEf, ln1g, ln1b, T, SN);

  for (int a = 0; a < 10; ++a) {
    scan_k<<<dim3(16, 3), 256, 0, stream>>>(SN, PSb);
    // S1 partials = PS @ Wvo[a]^T  (split-K x2)
    gemm_d<64, EPI_PART><<<dim3(64, 6, 2), 256, 0, stream>>>(
        PSb, Wvo + (size_t)a * 589824, Part, nullptr, nullptr, 768, 768, 384, 384, 0, 0, 3145728);
    reduce_ln<2, 1><<<4096, 256, 0, stream>>>(Part, 3145728, T, ln2g, ln2b, nullptr, SN);
    gemm_d<128, EPI_GELU><<<dim3(32, 24, 1), 256, 0, stream>>>(
        SN, Wb_f1, nullptr, H, fc1b, 768, 3072, 0, 768, 0, 0, 0);
    gemm_d<64, EPI_PART><<<dim3(64, 6, 2), 256, 0, stream>>>(
        H, Wb_f2, Part, nullptr, nullptr, 3072, 768, 1536, 1536, 0, 0, 3145728);
    if (a < 9)
      reduce_ln<2, 2><<<4096, 256, 0, stream>>>(Part, 3145728, fc2b, ln1g, ln1b, T, SN);
    else
      reduce_ln<2, 3><<<4096, 256, 0, stream>>>(Part, 3145728, fc2b, nullptr, nullptr, out, nullptr);
  }
  (void)in_sizes; (void)n_in; (void)out_size; (void)ws_size;
}

// Round 6
// 1358.928 us; speedup vs baseline: 1.9339x; 1.9339x over previous
//
#include <hip/hip_runtime.h>
#include <hip/hip_bf16.h>
#include <math.h>

// RTM identities:
//  - softmax over size-1 axis == 1  =>  q,k,Wq,Wk dead; newV == v
//  - token j restarts from s0[:,j]; only cumV couples tokens
//  - prefix-sum linear => fold Wv into Wo: Wvo[a] = Wo[a] @ Wv[a] (once);
//       S1 = PS(LN1(T)) @ Wvo[a]^T + T
// R6: back to R4's LDS+swizzle+dbuf GEMM (R5's no-LDS direct-fragment path
// was 2.7x slower: 16-line scatter per load + 2x duplicate loads + no latency
// hiding). R6 change: BN=64 tiles everywhere + fc2 split-K x4 so every big
// GEMM runs 1536 blocks (6/CU at 24KB LDS) — attacks the measured
// latency-bound profile (MfmaUtil 15%, all pipes idle) with occupancy.
// NOTE: __syncthreads drains vmcnt(0), so prefetch distance is capped at one
// inter-barrier interval regardless of buffer count — don't triple-buffer.

using bf16   = __bf16;
using bf16x8 = __attribute__((ext_vector_type(8))) __bf16;
using f32x4  = __attribute__((ext_vector_type(4))) float;

#define DEV __device__ __forceinline__

DEV void gload16(const bf16* g, bf16* l) {
  __builtin_amdgcn_global_load_lds(
      (const __attribute__((address_space(1))) unsigned int*)g,
      (__attribute__((address_space(3))) unsigned int*)l, 16, 0, 0);
}

// GELU with A&S 7.1.26 erf (abs err 1.5e-7; << bf16 rounding).
DEV float gelu_f(float x) {
  const float y  = x * 0.70710678118654752f;
  const float ay = fabsf(y);
  const float t  = __builtin_amdgcn_rcpf(__builtin_fmaf(0.3275911f, ay, 1.0f));
  float p = __builtin_fmaf(1.061405429f, t, -1.453152027f);
  p = __builtin_fmaf(p, t, 1.421413741f);
  p = __builtin_fmaf(p, t, -0.284496736f);
  p = __builtin_fmaf(p, t, 0.254829592f);
  p = p * t;
  const float e = __expf(-ay * ay);
  float er = __builtin_fmaf(-p, e, 1.0f);
  er = __builtin_copysignf(er, y);
  return 0.5f * x * (1.0f + er);
}

enum { EPI_PART = 0, EPI_GELU = 1, EPI_B16 = 2 };

// C[128 x BN tile] = A[M,K(+z*aZ)] @ B[N,K(+z*bZ)]^T over k in [z*kZ, z*kZ+klen).
// LDS: row-major [row][4 slots x 8 bf16]; slot s of row r holds global chunk
// kq = (s - (r>>1)) & 3  (swizzle -> 2-way bank floor, free per m136).
template <int BN, int EPI>
__global__ __launch_bounds__(256, 4) void gemm_k(
    const bf16* __restrict__ A, const bf16* __restrict__ B,
    float* __restrict__ outF, bf16* __restrict__ outB,
    const float* __restrict__ aux, int K, int N,
    int kZ, int klen, size_t aZ, size_t bZ, size_t oZ)
{
  constexpr int ABUF = 128 * 32;
  constexpr int BBUF = BN * 32;
  __shared__ bf16 As[2 * ABUF];
  __shared__ bf16 Bs[2 * BBUF];
  const int z = blockIdx.z;
  A += (size_t)z * aZ;
  B += (size_t)z * bZ;
  const int kbeg = z * kZ;
  const int tid  = threadIdx.x;
  const int lane = tid & 63, wave = tid >> 6;
  const int m0 = blockIdx.x * 128, n0 = blockIdx.y * BN;

  // Staging: thread tid covers row r = tid>>2, physical slot tid&3; chunk
  // kq = ((tid&3) - (r>>1)) & 3 — permutation within one 64B line.
  const int r  = tid >> 2;
  const int kq = ((tid & 3) - (tid >> 3)) & 3;
  const bf16* aG0 = A + (size_t)(m0 + r) * K + kq * 8 + kbeg;
  const bf16* aG1 = aG0 + (size_t)64 * K;
  const bf16* bG0 = B + (size_t)(n0 + r) * K + kq * 8 + kbeg;
  const bf16* bG1 = bG0 + (size_t)64 * K;   // only for BN==128

  const int wr = (wave & 1) * 64, wc = (wave >> 1) * (BN / 2);
  const int lr = lane & 15, kb = lane >> 4;
  const int swz  = ((kb + (lr >> 1)) & 3) * 8;
  const int aOff = (wr + lr) * 32 + swz;
  const int bOff = (wc + lr) * 32 + swz;

  constexpr int MT = 4, NT = BN / 32;
  f32x4 acc[MT][NT] = {};
  const int iters = klen >> 5;

  auto stage = [&](int p, int k0) {
    bf16* aD = &As[p * ABUF + tid * 8];
    gload16(aG0 + k0, aD);
    gload16(aG1 + k0, aD + 2048);
    bf16* bD = &Bs[p * BBUF + tid * 8];
    gload16(bG0 + k0, bD);
    if (BN == 128) gload16(bG1 + k0, bD + 2048);
  };

  stage(0, 0);
  for (int it = 0; it < iters; ++it) {
    __syncthreads();                       // tile `it` arrived
    if (it + 1 < iters) stage((it + 1) & 1, (it + 1) * 32);  // overlaps MFMA
    const int pa = (it & 1) * ABUF, pb = (it & 1) * BBUF;
    bf16x8 af[MT], bfv[NT];
#pragma unroll
    for (int t = 0; t < MT; ++t) af[t] = *(const bf16x8*)&As[pa + aOff + t * 512];
#pragma unroll
    for (int t = 0; t < NT; ++t) bfv[t] = *(const bf16x8*)&Bs[pb + bOff + t * 512];
#pragma unroll
    for (int mt = 0; mt < MT; ++mt)
#pragma unroll
      for (int nt = 0; nt < NT; ++nt)
        acc[mt][nt] = __builtin_amdgcn_mfma_f32_16x16x32_bf16(af[mt], bfv[nt], acc[mt][nt], 0, 0, 0);
  }

  // C/D layout: col = lane&15, row = (lane>>4)*4 + reg  [verified m89/m91]
  const int row0 = m0 + wr + (lane >> 4) * 4;
  const int col0 = n0 + wc + lr;
  float* oF = (EPI == EPI_PART) ? outF + (size_t)z * oZ : nullptr;
  bf16*  oB = (EPI == EPI_B16)  ? outB + (size_t)z * oZ : outB;
#pragma unroll
  for (int mt = 0; mt < MT; ++mt) {
#pragma unroll
    for (int nt = 0; nt < NT; ++nt) {
      const int col = col0 + nt * 16;
      float bias = 0.f;
      if (EPI == EPI_GELU) bias = aux[col];
#pragma unroll
      for (int rg = 0; rg < 4; ++rg) {
        const int row = row0 + mt * 16 + rg;
        float v = acc[mt][nt][rg];
        if (EPI == EPI_PART) {
          oF[(size_t)row * N + col] = v;
        } else if (EPI == EPI_GELU) {
          oB[(size_t)row * N + col] = (bf16)gelu_f(v + bias);
        } else {
          oB[(size_t)row * N + col] = (bf16)v;
        }
      }
    }
  }
}

// One 768-row per block; sums NP split-K partials, adds per-MODE term, LN-fuses.
// MODE 0: s = Σp + PE[row&255]; T=s; SN = LN1(s)
// MODE 1: s = Σp + add[row]   ; SN = LN2(s)+s
// MODE 2: s = Σp + bias       ; T=s; SN = LN1(s)
// MODE 3: s = Σp + bias       ; T=s (fp32 out only, last stage)
template <int NP, int MODE>
__global__ __launch_bounds__(256) void reduce_ln(
    const float* __restrict__ P, size_t pZ,
    const float* __restrict__ add, const float* __restrict__ g,
    const float* __restrict__ b, float* __restrict__ Tout,
    bf16* __restrict__ SNout)
{
  const int row = blockIdx.x, t = threadIdx.x;
  float v[3];
#pragma unroll
  for (int c = 0; c < 3; ++c) {
    const int col = t + c * 256;
    float s = P[(size_t)row * 768 + col];
#pragma unroll
    for (int p = 1; p < NP; ++p) s += P[(size_t)p * pZ + (size_t)row * 768 + col];
    if (MODE == 0) s += add[(row & 255) * 768 + col];
    if (MODE == 1) s += add[(size_t)row * 768 + col];
    if (MODE == 2 || MODE == 3) s += add[col];
    v[c] = s;
  }
  if (MODE != 1) {
#pragma unroll
    for (int c = 0; c < 3; ++c) Tout[(size_t)row * 768 + t + c * 256] = v[c];
  }
  if (MODE == 3) return;

  __shared__ float red[8];
  float s = v[0] + v[1] + v[2];
#pragma unroll
  for (int o = 32; o >= 1; o >>= 1) s += __shfl_down(s, o);
  if ((t & 63) == 0) red[t >> 6] = s;
  __syncthreads();
  const float mu = (red[0] + red[1] + red[2] + red[3]) * (1.f / 768.f);
  const float d0 = v[0] - mu, d1 = v[1] - mu, d2 = v[2] - mu;
  float q = d0 * d0 + d1 * d1 + d2 * d2;
#pragma unroll
  for (int o = 32; o >= 1; o >>= 1) q += __shfl_down(q, o);
  if ((t & 63) == 0) red[4 + (t >> 6)] = q;
  __syncthreads();
  const float var = (red[4] + red[5] + red[6] + red[7]) * (1.f / 768.f);
  const float rs = rsqrtf(var + 1e-5f);
  float y0 = d0 * rs * g[t] + b[t];
  float y1 = d1 * rs * g[t + 256] + b[t + 256];
  float y2 = d2 * rs * g[t + 512] + b[t + 512];
  if (MODE == 1) { y0 += v[0]; y1 += v[1]; y2 += v[2]; }
  bf16* o = SNout + (size_t)row * 768;
  o[t] = (bf16)y0; o[t + 256] = (bf16)y1; o[t + 512] = (bf16)y2;
}

// Exclusive prefix over token axis j (256 tokens) of SN[n,j,d], bf16 io.
__global__ __launch_bounds__(256) void scan_partial_b(
    const bf16* __restrict__ SN, float* __restrict__ Ps)
{
  const int n = blockIdx.x, ch = blockIdx.y, d = blockIdx.z * 256 + threadIdx.x;
  const bf16* base = SN + ((size_t)(n * 256 + ch * 16)) * 768 + d;
  float s = 0.f;
#pragma unroll
  for (int j = 0; j < 16; ++j) s += (float)base[(size_t)j * 768];
  Ps[(size_t)(n * 16 + ch) * 768 + d] = s;
}

__global__ __launch_bounds__(256) void scan_final_b(
    const bf16* __restrict__ SN, const float* __restrict__ Ps,
    bf16* __restrict__ PSb)
{
  const int n = blockIdx.x, ch = blockIdx.y, d = blockIdx.z * 256 + threadIdx.x;
  float run = 0.f;
  for (int c = 0; c < ch; ++c) run += Ps[(size_t)(n * 16 + c) * 768 + d];
  const bf16* vb = SN + ((size_t)(n * 256 + ch * 16)) * 768 + d;
  bf16* ob = PSb + ((size_t)(n * 256 + ch * 16)) * 768 + d;
#pragma unroll
  for (int j = 0; j < 16; ++j) {
    ob[(size_t)j * 768] = (bf16)run;
    run += (float)vb[(size_t)j * 768];
  }
}

// WvT[a][n][k] = (bf16)Wv[a][k][n]; 64x64 tiles via LDS (65-float stride).
__global__ __launch_bounds__(256) void transpose_wv(
    const float* __restrict__ Wv, bf16* __restrict__ WvT)
{
  __shared__ float tile[64][65];
  const int a = blockIdx.z, k0 = blockIdx.x * 64, n0 = blockIdx.y * 64;
  const int c = threadIdx.x & 63, r4 = threadIdx.x >> 6;
  const float* src = Wv + (size_t)a * 589824;
  bf16* dst = WvT + (size_t)a * 589824;
#pragma unroll
  for (int i = 0; i < 16; ++i)
    tile[r4 + i * 4][c] = src[(size_t)(k0 + r4 + i * 4) * 768 + n0 + c];
  __syncthreads();
#pragma unroll
  for (int i = 0; i < 16; ++i) {
    const int n = r4 + i * 4;
    dst[(size_t)(n0 + n) * 768 + k0 + c] = (bf16)tile[c][n];
  }
}

__global__ __launch_bounds__(256) void f32_to_bf16_k(
    const float* __restrict__ in, bf16* __restrict__ out, int n4)
{
  const int i = blockIdx.x * 256 + threadIdx.x;
  if (i >= n4) return;
  const float4 v = ((const float4*)in)[i];
  bf16 h[4] = {(bf16)v.x, (bf16)v.y, (bf16)v.z, (bf16)v.w};
  *(uint2*)(out + 4 * (size_t)i) = *(uint2*)h;
}

// pe[j, 2p] = sin(j / 10000^(4p/768)),  pe[j, 2p+1] = cos(...)
__global__ __launch_bounds__(256) void pe_kernel(float* __restrict__ PE)
{
  const int id = blockIdx.x * 256 + threadIdx.x;  // 256*384 total
  const int j = id / 384, p = id % 384;
  const double ang = (double)j * pow(10000.0, -4.0 * (double)p / 768.0);
  PE[(size_t)j * 768 + 2 * p]     = (float)sin(ang);
  PE[(size_t)j * 768 + 2 * p + 1] = (float)cos(ang);
}

extern "C" void kernel_launch(void* const* d_in, const int* in_sizes, int n_in,
                              void* d_out, int out_size, void* d_ws, size_t ws_size,
                              hipStream_t stream)
{
  const float* x      = (const float*)d_in[0];
  const float* weight = (const float*)d_in[1];
  const float* Wv     = (const float*)d_in[4];
  const float* Wo     = (const float*)d_in[5];
  const float* ln1g   = (const float*)d_in[6];
  const float* ln1b   = (const float*)d_in[7];
  const float* ln2g   = (const float*)d_in[8];
  const float* ln2b   = (const float*)d_in[9];
  const float* fc1w   = (const float*)d_in[10];
  const float* fc1b   = (const float*)d_in[11];
  const float* fc2w   = (const float*)d_in[12];
  const float* fc2b   = (const float*)d_in[13];
  float* out = (float*)d_out;

  char* p = (char*)d_ws;
  auto alloc = [&](size_t bytes) { char* r = p; p += (bytes + 255) & ~(size_t)255; return r; };
  bf16*  Wb_w  = (bf16*)alloc(589824ull * 2);
  bf16*  Wb_o  = (bf16*)alloc(5898240ull * 2);
  bf16*  WvT   = (bf16*)alloc(5898240ull * 2);
  bf16*  Wvo   = (bf16*)alloc(5898240ull * 2);
  bf16*  Wb_f1 = (bf16*)alloc(2359296ull * 2);
  bf16*  Wb_f2 = (bf16*)alloc(2359296ull * 2);
  bf16*  Xb    = (bf16*)alloc(3145728ull * 2);
  float* PEf   = (float*)alloc(196608ull * 4);
  float* T     = (float*)alloc(3145728ull * 4);
  bf16*  SN    = (bf16*)alloc(3145728ull * 2);
  bf16*  PSb   = (bf16*)alloc(3145728ull * 2);
  bf16*  H     = (bf16*)alloc(12582912ull * 2);
  float* Ps    = (float*)alloc(196608ull * 4);
  float* Part  = (float*)alloc(4ull * 3145728ull * 4);

  auto cvt = [&](const float* src, bf16* dst, int n) {
    int n4 = n / 4;
    f32_to_bf16_k<<<(n4 + 255) / 256, 256, 0, stream>>>(src, dst, n4);
  };
  cvt(x, Xb, 3145728);
  cvt(weight, Wb_w, 589824);
  cvt(Wo, Wb_o, 5898240);
  cvt(fc1w, Wb_f1, 2359296);
  cvt(fc2w, Wb_f2, 2359296);
  transpose_wv<<<dim3(12, 12, 10), 256, 0, stream>>>(Wv, WvT);
  pe_kernel<<<384, 256, 0, stream>>>(PEf);

  // Wvo[a] = Wo[a] @ Wv[a]  (A = Wo[a][m,t], B = WvT[a][k,t], batched over z)
  gemm_k<64, EPI_B16><<<dim3(6, 12, 10), 256, 0, stream>>>(
      Wb_o, WvT, nullptr, Wvo, nullptr, 768, 768, 0, 768, 589824, 589824, 589824);

  // T0 = x @ weight^T + PE (split-K x2), fused LN1
  gemm_k<64, EPI_PART><<<dim3(32, 12, 2), 256, 0, stream>>>(
      Xb, Wb_w, Part, nullptr, nullptr, 768, 768, 384, 384, 0, 0, 3145728);
  reduce_ln<2, 0><<<4096, 256, 0, stream>>>(Part, 3145728, PEf, ln1g, ln1b, T, SN);

  for (int a = 0; a < 10; ++a) {
    scan_partial_b<<<dim3(16, 16, 3), 256, 0, stream>>>(SN, Ps);
    scan_final_b<<<dim3(16, 16, 3), 256, 0, stream>>>(SN, Ps, PSb);
    // S1 partials = PS @ Wvo[a]^T  (split-K x2)
    gemm_k<64, EPI_PART><<<dim3(32, 12, 2), 256, 0, stream>>>(
        PSb, Wvo + (size_t)a * 589824, Part, nullptr, nullptr, 768, 768, 384, 384, 0, 0, 3145728);
    reduce_ln<2, 1><<<4096, 256, 0, stream>>>(Part, 3145728, T, ln2g, ln2b, nullptr, SN);
    // fc1: 1536 blocks (6/CU), BN=64
    gemm_k<64, EPI_GELU><<<dim3(32, 48, 1), 256, 0, stream>>>(
        SN, Wb_f1, nullptr, H, fc1b, 768, 3072, 0, 768, 0, 0, 0);
    // fc2: split-K x4 -> 1536 blocks x 24 iters
    gemm_k<64, EPI_PART><<<dim3(32, 12, 4), 256, 0, stream>>>(
        H, Wb_f2, Part, nullptr, nullptr, 3072, 768, 768, 768, 0, 0, 3145728);
    if (a < 9)
      reduce_ln<4, 2><<<4096, 256, 0, stream>>>(Part, 3145728, fc2b, ln1g, ln1b, T, SN);
    else
      reduce_ln<4, 3><<<4096, 256, 0, stream>>>(Part, 3145728, fc2b, nullptr, nullptr, out, nullptr);
  }
  (void)in_sizes; (void)n_in; (void)out_size; (void)ws_size;
}

// Round 7
// 1323.269 us; speedup vs baseline: 1.9860x; 1.0269x over previous
//
#include <hip/hip_runtime.h>
#include <hip/hip_bf16.h>
#include <math.h>

// RTM identities:
//  - softmax over size-1 axis == 1  =>  q,k,Wq,Wk dead; newV == v
//  - token j restarts from s0[:,j]; only cumV couples tokens
//  - prefix-sum linear => fold Wv into Wo: Wvo[a] = Wo[a] @ Wv[a] (once);
//       S1 = PS(LN1(T)) @ Wvo[a]^T + T
// R7 = R4 (1253us, best) + (a) fc1 BN=96 -> 1024 blocks = 4/CU (R4 fc1 was
// grid-limited at exactly 3/CU), (b) fc2 split-K x2 / NP=2 (R6's x4 added
// 25MB partial traffic for nothing), (c) reduce_ln vectorized float4/192thr.
// History: BN=64 everywhere (R6) regressed — wave-tile register reuse
// (MFMA per LDS byte) dominates over occupancy; no-LDS direct frags (R5)
// regressed 2.7x — L2 latency unhidable in-wave.

using bf16   = __bf16;
using bf16x8 = __attribute__((ext_vector_type(8))) __bf16;
using f32x4  = __attribute__((ext_vector_type(4))) float;

#define DEV __device__ __forceinline__

DEV void gload16(const bf16* g, bf16* l) {
  __builtin_amdgcn_global_load_lds(
      (const __attribute__((address_space(1))) unsigned int*)g,
      (__attribute__((address_space(3))) unsigned int*)l, 16, 0, 0);
}

// GELU with A&S 7.1.26 erf (abs err 1.5e-7; << bf16 rounding).
DEV float gelu_f(float x) {
  const float y  = x * 0.70710678118654752f;
  const float ay = fabsf(y);
  const float t  = __builtin_amdgcn_rcpf(__builtin_fmaf(0.3275911f, ay, 1.0f));
  float p = __builtin_fmaf(1.061405429f, t, -1.453152027f);
  p = __builtin_fmaf(p, t, 1.421413741f);
  p = __builtin_fmaf(p, t, -0.284496736f);
  p = __builtin_fmaf(p, t, 0.254829592f);
  p = p * t;
  const float e = __expf(-ay * ay);
  float er = __builtin_fmaf(-p, e, 1.0f);
  er = __builtin_copysignf(er, y);
  return 0.5f * x * (1.0f + er);
}

enum { EPI_PART = 0, EPI_GELU = 1, EPI_B16 = 2 };

// C[128 x BN tile] = A[M,K(+z*aZ)] @ B[N,K(+z*bZ)]^T over k in [z*kZ, z*kZ+klen).
// LDS: row-major [row][4 slots x 8 bf16]; slot s of row r holds global chunk
// kq = (s - (r>>1)) & 3  (swizzle -> 2-way bank floor, free per m136).
// BN in {64, 96, 128}.
template <int BN, int EPI>
__global__ __launch_bounds__(256) void gemm_k(
    const bf16* __restrict__ A, const bf16* __restrict__ B,
    float* __restrict__ outF, bf16* __restrict__ outB,
    const float* __restrict__ aux, int K, int N,
    int kZ, int klen, size_t aZ, size_t bZ, size_t oZ)
{
  constexpr int ABUF = 128 * 32;
  constexpr int BBUF = BN * 32;
  __shared__ bf16 As[2 * ABUF];
  __shared__ bf16 Bs[2 * BBUF];
  const int z = blockIdx.z;
  A += (size_t)z * aZ;
  B += (size_t)z * bZ;
  const int kbeg = z * kZ;
  const int tid  = threadIdx.x;
  const int lane = tid & 63, wave = tid >> 6;
  const int m0 = blockIdx.x * 128, n0 = blockIdx.y * BN;

  // Staging: thread tid covers row r = tid>>2, physical slot tid&3; chunk
  // kq = ((tid&3) - (r>>1)) & 3 — permutation within one 64B line.
  const int r  = tid >> 2;
  const int kq = ((tid & 3) - (tid >> 3)) & 3;
  const bf16* aG0 = A + (size_t)(m0 + r) * K + kq * 8 + kbeg;
  const bf16* aG1 = aG0 + (size_t)64 * K;
  const bf16* bG0 = B + (size_t)(n0 + r) * K + kq * 8 + kbeg;
  const bf16* bG1 = bG0 + (size_t)64 * K;   // rows 64.. (BN>64 only)

  const int wr = (wave & 1) * 64, wc = (wave >> 1) * (BN / 2);
  const int lr = lane & 15, kb = lane >> 4;
  const int swz  = ((kb + (lr >> 1)) & 3) * 8;
  const int aOff = (wr + lr) * 32 + swz;
  const int bOff = (wc + lr) * 32 + swz;

  constexpr int MT = 4, NT = BN / 32;
  f32x4 acc[MT][NT] = {};
  const int iters = klen >> 5;

  auto stage = [&](int p, int k0) {
    bf16* aD = &As[p * ABUF + tid * 8];
    gload16(aG0 + k0, aD);
    gload16(aG1 + k0, aD + 2048);
    bf16* bD = &Bs[p * BBUF + tid * 8];
    gload16(bG0 + k0, bD);
    if (BN == 128) gload16(bG1 + k0, bD + 2048);
    if (BN == 96) { if (tid < 128) gload16(bG1 + k0, bD + 2048); }
  };

  stage(0, 0);
  for (int it = 0; it < iters; ++it) {
    __syncthreads();                       // tile `it` arrived
    if (it + 1 < iters) stage((it + 1) & 1, (it + 1) * 32);  // overlaps MFMA
    const int pa = (it & 1) * ABUF, pb = (it & 1) * BBUF;
    bf16x8 af[MT], bfv[NT];
#pragma unroll
    for (int t = 0; t < MT; ++t) af[t] = *(const bf16x8*)&As[pa + aOff + t * 512];
#pragma unroll
    for (int t = 0; t < NT; ++t) bfv[t] = *(const bf16x8*)&Bs[pb + bOff + t * 512];
#pragma unroll
    for (int mt = 0; mt < MT; ++mt)
#pragma unroll
      for (int nt = 0; nt < NT; ++nt)
        acc[mt][nt] = __builtin_amdgcn_mfma_f32_16x16x32_bf16(af[mt], bfv[nt], acc[mt][nt], 0, 0, 0);
  }

  // C/D layout: col = lane&15, row = (lane>>4)*4 + reg  [verified m89/m91]
  const int row0 = m0 + wr + (lane >> 4) * 4;
  const int col0 = n0 + wc + lr;
  float* oF = (EPI == EPI_PART) ? outF + (size_t)z * oZ : nullptr;
  bf16*  oB = (EPI == EPI_B16)  ? outB + (size_t)z * oZ : outB;
#pragma unroll
  for (int mt = 0; mt < MT; ++mt) {
#pragma unroll
    for (int nt = 0; nt < NT; ++nt) {
      const int col = col0 + nt * 16;
      float bias = 0.f;
      if (EPI == EPI_GELU) bias = aux[col];
#pragma unroll
      for (int rg = 0; rg < 4; ++rg) {
        const int row = row0 + mt * 16 + rg;
        float v = acc[mt][nt][rg];
        if (EPI == EPI_PART) {
          oF[(size_t)row * N + col] = v;
        } else if (EPI == EPI_GELU) {
          oB[(size_t)row * N + col] = (bf16)gelu_f(v + bias);
        } else {
          oB[(size_t)row * N + col] = (bf16)v;
        }
      }
    }
  }
}

// One 768-row per block, 192 threads, float4-vectorized.
// Sums NP split-K partials, adds per-MODE term, LN-fuses.
// MODE 0: s = Σp + PE[row&255]; T=s; SN = LN1(s)
// MODE 1: s = Σp + add[row]   ; SN = LN2(s)+s
// MODE 2: s = Σp + bias       ; T=s; SN = LN1(s)
// MODE 3: s = Σp + bias       ; T=s (fp32 out only, last stage)
template <int NP, int MODE>
__global__ __launch_bounds__(192) void reduce_ln(
    const float* __restrict__ P, size_t pZ,
    const float* __restrict__ add, const float* __restrict__ g,
    const float* __restrict__ b, float* __restrict__ Tout,
    bf16* __restrict__ SNout)
{
  const int row = blockIdx.x, v = threadIdx.x;   // v in [0,192)
  float4 s = ((const float4*)(P + (size_t)row * 768))[v];
#pragma unroll
  for (int p = 1; p < NP; ++p) {
    const float4 t = ((const float4*)(P + (size_t)p * pZ + (size_t)row * 768))[v];
    s.x += t.x; s.y += t.y; s.z += t.z; s.w += t.w;
  }
  if (MODE == 0) {
    const float4 t = ((const float4*)(add + (size_t)(row & 255) * 768))[v];
    s.x += t.x; s.y += t.y; s.z += t.z; s.w += t.w;
  }
  if (MODE == 1) {
    const float4 t = ((const float4*)(add + (size_t)row * 768))[v];
    s.x += t.x; s.y += t.y; s.z += t.z; s.w += t.w;
  }
  if (MODE == 2 || MODE == 3) {
    const float4 t = ((const float4*)add)[v];
    s.x += t.x; s.y += t.y; s.z += t.z; s.w += t.w;
  }
  if (MODE != 1) ((float4*)(Tout + (size_t)row * 768))[v] = s;
  if (MODE == 3) return;

  __shared__ float red[6];
  float su = s.x + s.y + s.z + s.w;
#pragma unroll
  for (int o = 32; o >= 1; o >>= 1) su += __shfl_down(su, o);
  if ((v & 63) == 0) red[v >> 6] = su;
  __syncthreads();
  const float mu = (red[0] + red[1] + red[2]) * (1.f / 768.f);
  const float d0 = s.x - mu, d1 = s.y - mu, d2 = s.z - mu, d3 = s.w - mu;
  float q = d0 * d0 + d1 * d1 + d2 * d2 + d3 * d3;
#pragma unroll
  for (int o = 32; o >= 1; o >>= 1) q += __shfl_down(q, o);
  if ((v & 63) == 0) red[3 + (v >> 6)] = q;
  __syncthreads();
  const float var = (red[3] + red[4] + red[5]) * (1.f / 768.f);
  const float rs = rsqrtf(var + 1e-5f);
  const float4 g4 = ((const float4*)g)[v];
  const float4 b4 = ((const float4*)b)[v];
  float y0 = d0 * rs * g4.x + b4.x;
  float y1 = d1 * rs * g4.y + b4.y;
  float y2 = d2 * rs * g4.z + b4.z;
  float y3 = d3 * rs * g4.w + b4.w;
  if (MODE == 1) { y0 += s.x; y1 += s.y; y2 += s.z; y3 += s.w; }
  bf16 h[4] = {(bf16)y0, (bf16)y1, (bf16)y2, (bf16)y3};
  *(uint2*)(SNout + (size_t)row * 768 + 4 * v) = *(uint2*)h;
}

// Exclusive prefix over token axis j (256 tokens) of SN[n,j,d], bf16 io.
__global__ __launch_bounds__(256) void scan_partial_b(
    const bf16* __restrict__ SN, float* __restrict__ Ps)
{
  const int n = blockIdx.x, ch = blockIdx.y, d = blockIdx.z * 256 + threadIdx.x;
  const bf16* base = SN + ((size_t)(n * 256 + ch * 16)) * 768 + d;
  float s = 0.f;
#pragma unroll
  for (int j = 0; j < 16; ++j) s += (float)base[(size_t)j * 768];
  Ps[(size_t)(n * 16 + ch) * 768 + d] = s;
}

__global__ __launch_bounds__(256) void scan_final_b(
    const bf16* __restrict__ SN, const float* __restrict__ Ps,
    bf16* __restrict__ PSb)
{
  const int n = blockIdx.x, ch = blockIdx.y, d = blockIdx.z * 256 + threadIdx.x;
  float run = 0.f;
  for (int c = 0; c < ch; ++c) run += Ps[(size_t)(n * 16 + c) * 768 + d];
  const bf16* vb = SN + ((size_t)(n * 256 + ch * 16)) * 768 + d;
  bf16* ob = PSb + ((size_t)(n * 256 + ch * 16)) * 768 + d;
#pragma unroll
  for (int j = 0; j < 16; ++j) {
    ob[(size_t)j * 768] = (bf16)run;
    run += (float)vb[(size_t)j * 768];
  }
}

// WvT[a][n][k] = (bf16)Wv[a][k][n]; 64x64 tiles via LDS (65-float stride).
__global__ __launch_bounds__(256) void transpose_wv(
    const float* __restrict__ Wv, bf16* __restrict__ WvT)
{
  __shared__ float tile[64][65];
  const int a = blockIdx.z, k0 = blockIdx.x * 64, n0 = blockIdx.y * 64;
  const int c = threadIdx.x & 63, r4 = threadIdx.x >> 6;
  const float* src = Wv + (size_t)a * 589824;
  bf16* dst = WvT + (size_t)a * 589824;
#pragma unroll
  for (int i = 0; i < 16; ++i)
    tile[r4 + i * 4][c] = src[(size_t)(k0 + r4 + i * 4) * 768 + n0 + c];
  __syncthreads();
#pragma unroll
  for (int i = 0; i < 16; ++i) {
    const int n = r4 + i * 4;
    dst[(size_t)(n0 + n) * 768 + k0 + c] = (bf16)tile[c][n];
  }
}

__global__ __launch_bounds__(256) void f32_to_bf16_k(
    const float* __restrict__ in, bf16* __restrict__ out, int n4)
{
  const int i = blockIdx.x * 256 + threadIdx.x;
  if (i >= n4) return;
  const float4 v = ((const float4*)in)[i];
  bf16 h[4] = {(bf16)v.x, (bf16)v.y, (bf16)v.z, (bf16)v.w};
  *(uint2*)(out + 4 * (size_t)i) = *(uint2*)h;
}

// pe[j, 2p] = sin(j / 10000^(4p/768)),  pe[j, 2p+1] = cos(...)
__global__ __launch_bounds__(256) void pe_kernel(float* __restrict__ PE)
{
  const int id = blockIdx.x * 256 + threadIdx.x;  // 256*384 total
  const int j = id / 384, p = id % 384;
  const double ang = (double)j * pow(10000.0, -4.0 * (double)p / 768.0);
  PE[(size_t)j * 768 + 2 * p]     = (float)sin(ang);
  PE[(size_t)j * 768 + 2 * p + 1] = (float)cos(ang);
}

extern "C" void kernel_launch(void* const* d_in, const int* in_sizes, int n_in,
                              void* d_out, int out_size, void* d_ws, size_t ws_size,
                              hipStream_t stream)
{
  const float* x      = (const float*)d_in[0];
  const float* weight = (const float*)d_in[1];
  const float* Wv     = (const float*)d_in[4];
  const float* Wo     = (const float*)d_in[5];
  const float* ln1g   = (const float*)d_in[6];
  const float* ln1b   = (const float*)d_in[7];
  const float* ln2g   = (const float*)d_in[8];
  const float* ln2b   = (const float*)d_in[9];
  const float* fc1w   = (const float*)d_in[10];
  const float* fc1b   = (const float*)d_in[11];
  const float* fc2w   = (const float*)d_in[12];
  const float* fc2b   = (const float*)d_in[13];
  float* out = (float*)d_out;

  char* p = (char*)d_ws;
  auto alloc = [&](size_t bytes) { char* r = p; p += (bytes + 255) & ~(size_t)255; return r; };
  bf16*  Wb_w  = (bf16*)alloc(589824ull * 2);
  bf16*  Wb_o  = (bf16*)alloc(5898240ull * 2);
  bf16*  WvT   = (bf16*)alloc(5898240ull * 2);
  bf16*  Wvo   = (bf16*)alloc(5898240ull * 2);
  bf16*  Wb_f1 = (bf16*)alloc(2359296ull * 2);
  bf16*  Wb_f2 = (bf16*)alloc(2359296ull * 2);
  bf16*  Xb    = (bf16*)alloc(3145728ull * 2);
  float* PEf   = (float*)alloc(196608ull * 4);
  float* T     = (float*)alloc(3145728ull * 4);
  bf16*  SN    = (bf16*)alloc(3145728ull * 2);
  bf16*  PSb   = (bf16*)alloc(3145728ull * 2);
  bf16*  H     = (bf16*)alloc(12582912ull * 2);
  float* Ps    = (float*)alloc(196608ull * 4);
  float* Part  = (float*)alloc(2ull * 3145728ull * 4);

  auto cvt = [&](const float* src, bf16* dst, int n) {
    int n4 = n / 4;
    f32_to_bf16_k<<<(n4 + 255) / 256, 256, 0, stream>>>(src, dst, n4);
  };
  cvt(x, Xb, 3145728);
  cvt(weight, Wb_w, 589824);
  cvt(Wo, Wb_o, 5898240);
  cvt(fc1w, Wb_f1, 2359296);
  cvt(fc2w, Wb_f2, 2359296);
  transpose_wv<<<dim3(12, 12, 10), 256, 0, stream>>>(Wv, WvT);
  pe_kernel<<<384, 256, 0, stream>>>(PEf);

  // Wvo[a] = Wo[a] @ Wv[a]  (A = Wo[a][m,t], B = WvT[a][k,t], batched over z)
  gemm_k<128, EPI_B16><<<dim3(6, 6, 10), 256, 0, stream>>>(
      Wb_o, WvT, nullptr, Wvo, nullptr, 768, 768, 0, 768, 589824, 589824, 589824);

  // T0 = x @ weight^T + PE (split-K x2), fused LN1
  gemm_k<64, EPI_PART><<<dim3(32, 12, 2), 256, 0, stream>>>(
      Xb, Wb_w, Part, nullptr, nullptr, 768, 768, 384, 384, 0, 0, 3145728);
  reduce_ln<2, 0><<<4096, 192, 0, stream>>>(Part, 3145728, PEf, ln1g, ln1b, T, SN);

  for (int a = 0; a < 10; ++a) {
    scan_partial_b<<<dim3(16, 16, 3), 256, 0, stream>>>(SN, Ps);
    scan_final_b<<<dim3(16, 16, 3), 256, 0, stream>>>(SN, Ps, PSb);
    // S1 partials = PS @ Wvo[a]^T  (split-K x2)
    gemm_k<64, EPI_PART><<<dim3(32, 12, 2), 256, 0, stream>>>(
        PSb, Wvo + (size_t)a * 589824, Part, nullptr, nullptr, 768, 768, 384, 384, 0, 0, 3145728);
    reduce_ln<2, 1><<<4096, 192, 0, stream>>>(Part, 3145728, T, ln2g, ln2b, nullptr, SN);
    // fc1: BN=96 -> 32x32 = 1024 blocks (4/CU; R4's BN=128 was grid-capped at 3)
    gemm_k<96, EPI_GELU><<<dim3(32, 32, 1), 256, 0, stream>>>(
        SN, Wb_f1, nullptr, H, fc1b, 768, 3072, 0, 768, 0, 0, 0);
    // fc2: split-K x2 -> 768 blocks x 48 iters
    gemm_k<64, EPI_PART><<<dim3(32, 12, 2), 256, 0, stream>>>(
        H, Wb_f2, Part, nullptr, nullptr, 3072, 768, 1536, 1536, 0, 0, 3145728);
    if (a < 9)
      reduce_ln<2, 2><<<4096, 192, 0, stream>>>(Part, 3145728, fc2b, ln1g, ln1b, T, SN);
    else
      reduce_ln<2, 3><<<4096, 192, 0, stream>>>(Part, 3145728, fc2b, nullptr, nullptr, out, nullptr);
  }
  (void)in_sizes; (void)n_in; (void)out_size; (void)ws_size;
}